// Round 2
// baseline (198.412 us; speedup 1.0000x reference)
//
#include <hip/hip_runtime.h>

// SGE-style gate: B=64, C=512, HW=784, G=8, cpg=64.
// One block per (b,g) tile. Tile (64ch x 784pos = 196KB fp32) held in
// registers: 1024 threads x 49 floats. Single HBM read + single HBM write.
//
// R1 fix: __launch_bounds__(1024, 4) (was (1024,8)). The 8-waves/SIMD bound
// capped VGPRs at 64 -> the 49-float tile array spilled to scratch
// (VGPR_Count=32, WRITE_SIZE 119MB vs 98MB ideal, latency-bound at 70us).
// 4 waves/SIMD -> 128-VGPR cap -> tile stays in registers; 16 waves/CU is
// plenty of MLP for a streaming kernel (49 independent loads/thread).

#define HW   784
#define CPG  64
#define NG   8
#define KPT  49          // (CPG*HW)/1024 elements per thread

__global__ __launch_bounds__(1024, 4)
void sge_kernel(const float* __restrict__ x,
                const float* __restrict__ weight,
                const float* __restrict__ bias,
                float* __restrict__ out) {
    __shared__ float sbuf[16 * HW];   // wave-partials of s; row 0 reused for gate
    __shared__ float redbuf[32];      // block-reduce scratch (16 waves x {s, s^2})

    const int t    = threadIdx.x;
    const int c    = t >> 4;          // channel within group, 0..63
    const int j    = t & 15;          // sub-position, 0..15
    const int wave = t >> 6;          // 0..15
    const int lane = t & 63;

    const int bg = blockIdx.x;        // b*NG + g, 0..511 — group tile is contiguous
    const int g  = bg & (NG - 1);
    const size_t base = (size_t)bg * (CPG * HW);

    // ---- load tile slice into registers (one HBM read of x) ----
    const float* xp = x + base + (size_t)c * HW + j;
    float v[KPT];
#pragma unroll
    for (int k = 0; k < KPT; ++k) v[k] = xp[k * 16];

    // ---- per-channel spatial mean: 16 threads/channel, within one wave ----
    float cs = 0.f;
#pragma unroll
    for (int k = 0; k < KPT; ++k) cs += v[k];
    cs += __shfl_xor(cs, 1, 16);
    cs += __shfl_xor(cs, 2, 16);
    cs += __shfl_xor(cs, 4, 16);
    cs += __shfl_xor(cs, 8, 16);
    const float mean_c = cs * (1.0f / (float)HW);

    // ---- s[p] = sum_c v[c,p]*mean_c : intra-wave 4-channel partial ----
#pragma unroll
    for (int k = 0; k < KPT; ++k) {
        float w = v[k] * mean_c;
        w += __shfl_xor(w, 16, 64);   // sum the 4 channels resident in this wave
        w += __shfl_xor(w, 32, 64);
        if (lane < 16) sbuf[wave * HW + k * 16 + j] = w;  // p = j + 16k
    }
    __syncthreads();

    // ---- cross-wave sum: thread t (< 784) owns position p = t ----
    float s = 0.f;
    if (t < HW) {
#pragma unroll
        for (int w = 0; w < 16; ++w) s += sbuf[w * HW + t];
    }

    // ---- block reduction for mu, var over the 784 s values ----
    float rs = s, rs2 = s * s;
#pragma unroll
    for (int m = 1; m < 64; m <<= 1) {
        rs  += __shfl_xor(rs,  m, 64);
        rs2 += __shfl_xor(rs2, m, 64);
    }
    if (lane == 0) { redbuf[wave] = rs; redbuf[16 + wave] = rs2; }
    __syncthreads();

    float sum_s = 0.f, sum_s2 = 0.f;
#pragma unroll
    for (int w = 0; w < 16; ++w) { sum_s += redbuf[w]; sum_s2 += redbuf[16 + w]; }
    const float mu   = sum_s * (1.0f / (float)HW);
    const float var  = sum_s2 * (1.0f / (float)HW) - mu * mu;
    const float rstd = rsqrtf(var + 1e-5f);

    // ---- gate[p] = sigmoid(((s-mu)*rstd)*w_g + b_g), stored in sbuf row 0 ----
    const float wg = weight[g];
    const float bgv = bias[g];
    if (t < HW) {
        const float z = (s - mu) * rstd * wg + bgv;
        sbuf[t] = 1.0f / (1.0f + __expf(-z));
    }
    __syncthreads();

    // ---- epilogue: out = v * gate (gate read is an LDS broadcast) ----
    float* op = out + base + (size_t)c * HW + j;
#pragma unroll
    for (int k = 0; k < KPT; ++k) op[k * 16] = v[k] * sbuf[k * 16 + j];
}

extern "C" void kernel_launch(void* const* d_in, const int* in_sizes, int n_in,
                              void* d_out, int out_size, void* d_ws, size_t ws_size,
                              hipStream_t stream) {
    const float* x      = (const float*)d_in[0];
    const float* weight = (const float*)d_in[1];
    const float* bias   = (const float*)d_in[2];
    // d_in[3] = groups (int scalar) — fixed at 8, baked into the kernel.
    float* out = (float*)d_out;

    sge_kernel<<<dim3(512), dim3(1024), 0, stream>>>(x, weight, bias, out);
}

// Round 4
// 192.124 us; speedup vs baseline: 1.0327x; 1.0327x over previous
//
#include <hip/hip_runtime.h>

// SGE-style gate: B=64, C=512, HW=784, G=8, cpg=64.
// One block per (b,g) tile; 1024 threads; tile held in REGISTERS as float4.
//
// R2 post-mortem: compiler rematerialized the v[] loads (VGPR=40, no scratch)
// -> silently 3-pass, ~392MB combined traffic @ ~5.6TB/s = 70us. Fix: pin the
// loaded values with opaque asm so they cannot be re-loaded; float4 loads.
// 1024-thr block caps VGPR at 128 (16 waves = 4/SIMD); need ~90 -> fits.
// R3: broker timeout, no data — identical kernel resubmitted.
//
// Thread map: t = c*16 + j (c=0..63 channel, j=0..15). Thread owns float4
// columns q = j + 16k (k=0..11) plus tail q = 192+j for j<4 (196 float4/row).

#define HW    784
#define HW4   196
#define CPG   64
#define NG    8
#define K4    12
#define TAIL4 4

__global__ __launch_bounds__(1024, 4)
void sge_kernel(const float* __restrict__ x,
                const float* __restrict__ weight,
                const float* __restrict__ bias,
                float* __restrict__ out) {
    __shared__ float sbuf[16 * HW];   // wave-partials of s; row 0 reused for gate
    __shared__ float redbuf[32];

    const int t    = threadIdx.x;
    const int c    = t >> 4;
    const int j    = t & 15;
    const int wave = t >> 6;
    const int lane = t & 63;

    const int bg = blockIdx.x;
    const int g  = bg & (NG - 1);
    const size_t base4 = (size_t)bg * (CPG * HW4) + (size_t)c * HW4; // float4 units

    // ---- single HBM read of the tile into registers ----
    const float4* xp = (const float4*)x + base4;
    float4 v[K4 + 1];
#pragma unroll
    for (int k = 0; k < K4; ++k) v[k] = xp[j + 16 * k];
    v[K4] = (j < TAIL4) ? xp[192 + j] : make_float4(0.f, 0.f, 0.f, 0.f);
    // Pin: values become opaque asm outputs -> compiler cannot rematerialize
    // the global loads; with cap 128 VGPR it keeps them resident.
#pragma unroll
    for (int k = 0; k <= K4; ++k)
        asm volatile("" : "+v"(v[k].x), "+v"(v[k].y), "+v"(v[k].z), "+v"(v[k].w));

    // ---- per-channel spatial mean (16 threads/channel, intra-wave) ----
    float cs = 0.f;
#pragma unroll
    for (int k = 0; k <= K4; ++k) cs += (v[k].x + v[k].y) + (v[k].z + v[k].w);
    cs += __shfl_xor(cs, 1, 64);
    cs += __shfl_xor(cs, 2, 64);
    cs += __shfl_xor(cs, 4, 64);
    cs += __shfl_xor(cs, 8, 64);
    const float mean_c = cs * (1.0f / (float)HW);

    // ---- s partials: w = v*mean_c, summed over the wave's 4 channels ----
    float4* srow = (float4*)(sbuf + wave * HW);
#pragma unroll
    for (int k = 0; k <= K4; ++k) {
        float4 w;
        w.x = v[k].x * mean_c; w.y = v[k].y * mean_c;
        w.z = v[k].z * mean_c; w.w = v[k].w * mean_c;
        w.x += __shfl_xor(w.x, 16, 64); w.x += __shfl_xor(w.x, 32, 64);
        w.y += __shfl_xor(w.y, 16, 64); w.y += __shfl_xor(w.y, 32, 64);
        w.z += __shfl_xor(w.z, 16, 64); w.z += __shfl_xor(w.z, 32, 64);
        w.w += __shfl_xor(w.w, 16, 64); w.w += __shfl_xor(w.w, 32, 64);
        if (k < K4) {
            if (lane < 16) srow[j + 16 * k] = w;
        } else {
            if (lane < TAIL4) srow[192 + j] = w;   // lane==j<4 here
        }
    }
    __syncthreads();

    // ---- cross-wave sum: thread t (<784) owns position p = t ----
    float s = 0.f;
    if (t < HW) {
#pragma unroll
        for (int w = 0; w < 16; ++w) s += sbuf[w * HW + t];
    }

    // ---- block reduction for mu, var ----
    float rs = s, rs2 = s * s;
#pragma unroll
    for (int m = 1; m < 64; m <<= 1) {
        rs  += __shfl_xor(rs,  m, 64);
        rs2 += __shfl_xor(rs2, m, 64);
    }
    if (lane == 0) { redbuf[wave] = rs; redbuf[16 + wave] = rs2; }
    __syncthreads();

    float sum_s = 0.f, sum_s2 = 0.f;
#pragma unroll
    for (int w = 0; w < 16; ++w) { sum_s += redbuf[w]; sum_s2 += redbuf[16 + w]; }
    const float mu   = sum_s * (1.0f / (float)HW);
    const float var  = sum_s2 * (1.0f / (float)HW) - mu * mu;
    const float rstd = rsqrtf(var + 1e-5f);

    // ---- gate into sbuf row 0 ----
    const float wg  = weight[g];
    const float bgv = bias[g];
    if (t < HW) {
        const float z = (s - mu) * rstd * wg + bgv;
        sbuf[t] = 1.0f / (1.0f + __expf(-z));
    }
    __syncthreads();

    // ---- epilogue: out = v * gate (gate via LDS float4 broadcast) ----
    const float4* gate4 = (const float4*)sbuf;
    float4* op = (float4*)out + base4;
#pragma unroll
    for (int k = 0; k < K4; ++k) {
        const float4 gv = gate4[j + 16 * k];
        float4 o;
        o.x = v[k].x * gv.x; o.y = v[k].y * gv.y;
        o.z = v[k].z * gv.z; o.w = v[k].w * gv.w;
        op[j + 16 * k] = o;
    }
    if (j < TAIL4) {
        const float4 gv = gate4[192 + j];
        float4 o;
        o.x = v[K4].x * gv.x; o.y = v[K4].y * gv.y;
        o.z = v[K4].z * gv.z; o.w = v[K4].w * gv.w;
        op[192 + j] = o;
    }
}

extern "C" void kernel_launch(void* const* d_in, const int* in_sizes, int n_in,
                              void* d_out, int out_size, void* d_ws, size_t ws_size,
                              hipStream_t stream) {
    const float* x      = (const float*)d_in[0];
    const float* weight = (const float*)d_in[1];
    const float* bias   = (const float*)d_in[2];
    float* out = (float*)d_out;
    sge_kernel<<<dim3(512), dim3(1024), 0, stream>>>(x, weight, bias, out);
}